// Round 1
// 909.488 us; speedup vs baseline: 1.0734x; 1.0734x over previous
//
#include <hip/hip_runtime.h>
#include <hip/hip_bf16.h>
#include <cstddef>

typedef __bf16 bf16x8 __attribute__((ext_vector_type(8)));
typedef __bf16 bf16x4 __attribute__((ext_vector_type(4)));
typedef float f32x4 __attribute__((ext_vector_type(4)));

#define MFMA16(a, b, c) __builtin_amdgcn_mfma_f32_16x16x32_bf16((a), (b), (c), 0, 0, 0)

// ---------------- fp32 -> bf16 convert (X_q, X_k, X_v) ----------------
__global__ __launch_bounds__(256) void cvt3(const float* __restrict__ a,
                                            const float* __restrict__ b,
                                            const float* __restrict__ c,
                                            __bf16* __restrict__ oa,
                                            __bf16* __restrict__ ob,
                                            __bf16* __restrict__ oc) {
  const float* src = blockIdx.y == 0 ? a : (blockIdx.y == 1 ? b : c);
  __bf16* dst = blockIdx.y == 0 ? oa : (blockIdx.y == 1 ? ob : oc);
  const size_t i = ((size_t)blockIdx.x * 256 + threadIdx.x) * 4;
  float4 v = *(const float4*)(src + i);
  bf16x4 o = {(__bf16)v.x, (__bf16)v.y, (__bf16)v.z, (__bf16)v.w};
  *(bf16x4*)(dst + i) = o;
}

// ---------------- W [in][out] fp32 -> W^T [out][in] bf16 ----------------
__global__ __launch_bounds__(256) void twt(const float* __restrict__ w0, const float* __restrict__ w1,
                                           const float* __restrict__ w2, const float* __restrict__ w3,
                                           __bf16* __restrict__ o0, __bf16* __restrict__ o1,
                                           __bf16* __restrict__ o2, __bf16* __restrict__ o3) {
  const float* W;
  __bf16* O;
  switch (blockIdx.z) {
    case 0: W = w0; O = o0; break;
    case 1: W = w1; O = o1; break;
    case 2: W = w2; O = o2; break;
    default: W = w3; O = o3; break;
  }
  __shared__ float t[32][33];
  const int tx = threadIdx.x & 31, ty = threadIdx.x >> 5;
  const int bx = blockIdx.x * 32, by = blockIdx.y * 32;
#pragma unroll
  for (int i = 0; i < 4; ++i)
    t[ty + 8 * i][tx] = W[(size_t)(by + ty + 8 * i) * 1024 + bx + tx];
  __syncthreads();
#pragma unroll
  for (int i = 0; i < 4; ++i)
    O[(size_t)(bx + ty + 8 * i) * 1024 + by + tx] = (__bf16)t[tx][ty + 8 * i];
}

// ---------------- C = A @ B^T   (A: MxK bf16 row-major, B: NxK bf16 row-major) ---
// M = 4096 (grid.y*128), N = 1024, K = 1024. 128x128 tile, 4 waves, each wave 64x64.
template <bool OUT_BF16>
__global__ __launch_bounds__(256) void gemm_bt(const __bf16* __restrict__ A,
                                               const __bf16* __restrict__ B,
                                               void* __restrict__ Cout,
                                               const float* __restrict__ bias,
                                               float scale) {
  constexpr int K = 1024, N = 1024;
  const int tid = threadIdx.x, wave = tid >> 6, lane = tid & 63;
  const int qd = lane >> 4, ln = lane & 15;
  const int m0 = blockIdx.y * 128, n0 = blockIdx.x * 128;
  const int wr = wave >> 1, wc = wave & 1;

  __shared__ __align__(16) __bf16 sA[128][40];
  __shared__ __align__(16) __bf16 sB[128][40];

  f32x4 acc[4][4] = {};

  const int srow = tid >> 2, sch = (tid & 3) * 8;

  for (int k0 = 0; k0 < K; k0 += 32) {
    __syncthreads();
    *(bf16x8*)&sA[srow][sch]      = *(const bf16x8*)(A + (size_t)(m0 + srow) * K + k0 + sch);
    *(bf16x8*)&sA[srow + 64][sch] = *(const bf16x8*)(A + (size_t)(m0 + srow + 64) * K + k0 + sch);
    *(bf16x8*)&sB[srow][sch]      = *(const bf16x8*)(B + (size_t)(n0 + srow) * K + k0 + sch);
    *(bf16x8*)&sB[srow + 64][sch] = *(const bf16x8*)(B + (size_t)(n0 + srow + 64) * K + k0 + sch);
    __syncthreads();

    bf16x8 af[4], bfv[4];
#pragma unroll
    for (int i = 0; i < 4; ++i) af[i] = *(const bf16x8*)&sA[wr * 64 + i * 16 + ln][qd * 8];
#pragma unroll
    for (int j = 0; j < 4; ++j) bfv[j] = *(const bf16x8*)&sB[wc * 64 + j * 16 + ln][qd * 8];
#pragma unroll
    for (int i = 0; i < 4; ++i)
#pragma unroll
      for (int j = 0; j < 4; ++j) acc[i][j] = MFMA16(af[i], bfv[j], acc[i][j]);
  }

#pragma unroll
  for (int i = 0; i < 4; ++i)
#pragma unroll
    for (int j = 0; j < 4; ++j)
#pragma unroll
      for (int r = 0; r < 4; ++r) {
        const int row = m0 + wr * 64 + i * 16 + qd * 4 + r;
        const int col = n0 + wc * 64 + j * 16 + ln;
        float v = acc[i][j][r] * scale;
        if (bias) v += bias[col];
        if (OUT_BF16)
          ((__bf16*)Cout)[(size_t)row * N + col] = (__bf16)v;
        else
          ((float*)Cout)[(size_t)row * N + col] = v;
      }
}

// ---------------- fused sigmoid attention per (q-tile, head, batch) ----------------
// 64 q-rows per block, grid 32x16x2 = 1024 blocks -> 4 blocks/CU (LDS 34.5 KB).
// Q held in registers. S-tile 64x128 per iter; A written fp32 DIRECT from regs.
__global__ __launch_bounds__(256) void attn(const __bf16* __restrict__ Q,
                                            const __bf16* __restrict__ Kb,
                                            const __bf16* __restrict__ Vb,
                                            float* __restrict__ Aout,
                                            __bf16* __restrict__ Hc) {
  const int qt = blockIdx.x, h = blockIdx.y, b = blockIdx.z;
  const int tid = threadIdx.x, wave = tid >> 6, lane = tid & 63;
  const int qd = lane >> 4, ln = lane & 15;
  const int q0 = qt * 64;
  const int wr = wave >> 1, wc = wave & 1;

  // stride 132: V^T write conflicts 4-way (vs 8-way at 136); reads conflict-free via b64 pairs
  __shared__ __align__(16) __bf16 sVt[64][132];
  // aliased: K tile [128][72] (9216 el), then P tile [64][136] (8704 el)
  __shared__ __align__(16) __bf16 sKA[128 * 72];

  // Q fragments in registers for the whole kernel (16 VGPRs)
  const __bf16* Qg = Q + (size_t)(b * 2048 + q0) * 1024 + h * 64;
  bf16x8 qf[2][2];
#pragma unroll
  for (int i = 0; i < 2; ++i)
#pragma unroll
    for (int s = 0; s < 2; ++s)
      qf[i][s] = *(const bf16x8*)(Qg + (size_t)(wr * 32 + i * 16 + ln) * 1024 + s * 32 + qd * 8);

  f32x4 hacc[4] = {};
  float* Ag = Aout + ((size_t)((b * 16 + h) * 2048 + q0)) * 2048;

  for (int kt = 0; kt < 16; ++kt) {
    const int k0 = kt * 128;
    __syncthreads();  // prev iter's sKA(P)/sVt consumers done

    const __bf16* Kg = Kb + (size_t)(b * 2048 + k0) * 1024 + h * 64;
    const __bf16* Vg = Vb + (size_t)(b * 2048 + k0) * 1024 + h * 64;
#pragma unroll
    for (int p = 0; p < 4; ++p) {
      const int idx = p * 256 + tid, row = idx >> 3, ch = (idx & 7) * 8;
      *(bf16x8*)&sKA[row * 72 + ch] = *(const bf16x8*)(Kg + (size_t)row * 1024 + ch);
      bf16x8 v = *(const bf16x8*)(Vg + (size_t)row * 1024 + ch);
#pragma unroll
      for (int e = 0; e < 8; ++e) sVt[ch + e][row] = v[e];
    }
    __syncthreads();

    // S = Q·K^T : wave (wr,wc) owns 32 q-rows x 64 k-cols
    f32x4 sacc[2][4] = {};
#pragma unroll
    for (int ks = 0; ks < 64; ks += 32) {
      bf16x8 bfv[4];
#pragma unroll
      for (int j = 0; j < 4; ++j)
        bfv[j] = *(const bf16x8*)&sKA[(wc * 64 + j * 16 + ln) * 72 + ks + qd * 8];
#pragma unroll
      for (int i = 0; i < 2; ++i)
#pragma unroll
        for (int j = 0; j < 4; ++j) sacc[i][j] = MFMA16(qf[i][ks / 32], bfv[j], sacc[i][j]);
    }
    __syncthreads();  // all waves done reading K before aliasing as P

    // sigmoid -> direct fp32 A store (full precision) + bf16 P tile into sKA
#pragma unroll
    for (int i = 0; i < 2; ++i)
#pragma unroll
      for (int j = 0; j < 4; ++j)
#pragma unroll
        for (int r = 0; r < 4; ++r) {
          const float s = sacc[i][j][r];
          const float a = 1.0f / (1.0f + __expf(-s));
          const int rr = wr * 32 + i * 16 + qd * 4 + r;
          const int cc = wc * 64 + j * 16 + ln;
          Ag[(size_t)rr * 2048 + k0 + cc] = a;
          sKA[rr * 136 + cc] = (__bf16)a;
        }
    __syncthreads();

    // H += P·V : each wave owns 16 q-rows, all 64 d-cols
#pragma unroll
    for (int ks = 0; ks < 128; ks += 32) {
      bf16x8 pa = *(const bf16x8*)&sKA[(wave * 16 + ln) * 136 + ks + qd * 8];
#pragma unroll
      for (int j = 0; j < 4; ++j) {
        const __bf16* vp = &sVt[j * 16 + ln][ks + qd * 8];
        bf16x4 lo = *(const bf16x4*)vp;
        bf16x4 hi = *(const bf16x4*)(vp + 4);
        bf16x8 bv;
#pragma unroll
        for (int e = 0; e < 4; ++e) { bv[e] = lo[e]; bv[e + 4] = hi[e]; }
        hacc[j] = MFMA16(pa, bv, hacc[j]);
      }
    }
  }

  __bf16* Hg = Hc + (size_t)(b * 2048 + q0) * 1024 + h * 64;
#pragma unroll
  for (int j = 0; j < 4; ++j)
#pragma unroll
    for (int r = 0; r < 4; ++r)
      Hg[(size_t)(wave * 16 + qd * 4 + r) * 1024 + j * 16 + ln] = (__bf16)hacc[j][r];
}

extern "C" void kernel_launch(void* const* d_in, const int* in_sizes, int n_in,
                              void* d_out, int out_size, void* d_ws, size_t ws_size,
                              hipStream_t stream) {
  const float* Xq = (const float*)d_in[0];
  const float* Xk = (const float*)d_in[1];
  const float* Xv = (const float*)d_in[2];
  const float* Wq = (const float*)d_in[3];
  const float* Wk = (const float*)d_in[4];
  const float* Wv = (const float*)d_in[5];
  const float* Wh = (const float*)d_in[6];
  const float* bh = (const float*)d_in[7];

  float* Hout = (float*)d_out;               // 4096 x 1024 fp32
  float* Aout = Hout + (size_t)4096 * 1024;  // 2 x 16 x 2048 x 2048 fp32

  // workspace layout (bf16)
  __bf16* p = (__bf16*)d_ws;
  __bf16* Xq_bf = p; p += (size_t)4096 * 1024;
  __bf16* Xk_bf = p; p += (size_t)4096 * 1024;
  __bf16* Xv_bf = p; p += (size_t)4096 * 1024;
  __bf16* WqT = p; p += (size_t)1024 * 1024;
  __bf16* WkT = p; p += (size_t)1024 * 1024;
  __bf16* WvT = p; p += (size_t)1024 * 1024;
  __bf16* WhT = p; p += (size_t)1024 * 1024;
  __bf16* Qb = p; p += (size_t)4096 * 1024;
  __bf16* Kb = p; p += (size_t)4096 * 1024;
  __bf16* Vb = p; p += (size_t)4096 * 1024;
  __bf16* Hc = p; p += (size_t)4096 * 1024;

  cvt3<<<dim3(4096, 3), 256, 0, stream>>>(Xq, Xk, Xv, Xq_bf, Xk_bf, Xv_bf);
  twt<<<dim3(32, 32, 4), 256, 0, stream>>>(Wq, Wk, Wv, Wh, WqT, WkT, WvT, WhT);

  // Q gets the 1/sqrt(dk) = 0.125 scale fused in
  gemm_bt<true><<<dim3(8, 32), 256, 0, stream>>>(Xq_bf, WqT, (void*)Qb, nullptr, 0.125f);
  gemm_bt<true><<<dim3(8, 32), 256, 0, stream>>>(Xk_bf, WkT, (void*)Kb, nullptr, 1.0f);
  gemm_bt<true><<<dim3(8, 32), 256, 0, stream>>>(Xv_bf, WvT, (void*)Vb, nullptr, 1.0f);

  attn<<<dim3(32, 16, 2), 256, 0, stream>>>(Qb, Kb, Vb, Aout, Hc);

  gemm_bt<false><<<dim3(8, 32), 256, 0, stream>>>(Hc, WhT, (void*)Hout, bh, 1.0f);
}

// Round 2
// 866.240 us; speedup vs baseline: 1.1270x; 1.0499x over previous
//
#include <hip/hip_runtime.h>
#include <hip/hip_bf16.h>
#include <cstddef>

typedef __bf16 bf16x8 __attribute__((ext_vector_type(8)));
typedef __bf16 bf16x4 __attribute__((ext_vector_type(4)));
typedef float f32x4 __attribute__((ext_vector_type(4)));

#define MFMA16(a, b, c) __builtin_amdgcn_mfma_f32_16x16x32_bf16((a), (b), (c), 0, 0, 0)

// ---------------- fp32 -> bf16 convert (X_q, X_k, X_v) ----------------
__global__ __launch_bounds__(256) void cvt3(const float* __restrict__ a,
                                            const float* __restrict__ b,
                                            const float* __restrict__ c,
                                            __bf16* __restrict__ oa,
                                            __bf16* __restrict__ ob,
                                            __bf16* __restrict__ oc) {
  const float* src = blockIdx.y == 0 ? a : (blockIdx.y == 1 ? b : c);
  __bf16* dst = blockIdx.y == 0 ? oa : (blockIdx.y == 1 ? ob : oc);
  const size_t i = ((size_t)blockIdx.x * 256 + threadIdx.x) * 4;
  float4 v = *(const float4*)(src + i);
  bf16x4 o = {(__bf16)v.x, (__bf16)v.y, (__bf16)v.z, (__bf16)v.w};
  *(bf16x4*)(dst + i) = o;
}

// ---------------- W [in][out] fp32 -> W^T [out][in] bf16 ----------------
__global__ __launch_bounds__(256) void twt(const float* __restrict__ w0, const float* __restrict__ w1,
                                           const float* __restrict__ w2, const float* __restrict__ w3,
                                           __bf16* __restrict__ o0, __bf16* __restrict__ o1,
                                           __bf16* __restrict__ o2, __bf16* __restrict__ o3) {
  const float* W;
  __bf16* O;
  switch (blockIdx.z) {
    case 0: W = w0; O = o0; break;
    case 1: W = w1; O = o1; break;
    case 2: W = w2; O = o2; break;
    default: W = w3; O = o3; break;
  }
  __shared__ float t[32][33];
  const int tx = threadIdx.x & 31, ty = threadIdx.x >> 5;
  const int bx = blockIdx.x * 32, by = blockIdx.y * 32;
#pragma unroll
  for (int i = 0; i < 4; ++i)
    t[ty + 8 * i][tx] = W[(size_t)(by + ty + 8 * i) * 1024 + bx + tx];
  __syncthreads();
#pragma unroll
  for (int i = 0; i < 4; ++i)
    O[(size_t)(bx + ty + 8 * i) * 1024 + by + tx] = (__bf16)t[tx][ty + 8 * i];
}

// ---------------- C = A @ B^T  (64x128 tile, BK=64, 4 waves of 32x64) ----------
// A: Mx1024 bf16 row-major, B: 1024x1024 bf16 row-major (pre-transposed weights).
// grid.x = N/128 = 8, grid.y = M/64 = 64. LDS 27.6 KB -> 5 blocks/CU capacity.
template <bool OUT_BF16>
__device__ __forceinline__ void gemm64_body(const __bf16* __restrict__ A,
                                            const __bf16* __restrict__ B,
                                            void* __restrict__ Cout,
                                            const float* __restrict__ bias,
                                            float scale) {
  constexpr int K = 1024, N = 1024;
  const int tid = threadIdx.x, wave = tid >> 6, lane = tid & 63;
  const int qd = lane >> 4, ln = lane & 15;
  const int m0 = blockIdx.y * 64, n0 = blockIdx.x * 128;
  const int wr = wave & 1, wc = wave >> 1;

  __shared__ __align__(16) __bf16 sA[64][72];
  __shared__ __align__(16) __bf16 sB[128][72];

  f32x4 acc[2][4] = {};

  const int sr = tid >> 2, sc = (tid & 3) * 8;  // 4 lanes cover 64B contiguous

  for (int k0 = 0; k0 < K; k0 += 64) {
    __syncthreads();
    *(bf16x8*)&sA[sr][sc]      = *(const bf16x8*)(A + (size_t)(m0 + sr) * K + k0 + sc);
    *(bf16x8*)&sA[sr][sc + 32] = *(const bf16x8*)(A + (size_t)(m0 + sr) * K + k0 + sc + 32);
#pragma unroll
    for (int h = 0; h < 128; h += 64)
#pragma unroll
      for (int c = 0; c < 64; c += 32)
        *(bf16x8*)&sB[sr + h][sc + c] =
            *(const bf16x8*)(B + (size_t)(n0 + sr + h) * K + k0 + sc + c);
    __syncthreads();

#pragma unroll
    for (int ks = 0; ks < 64; ks += 32) {
      bf16x8 af[2], bfv[4];
#pragma unroll
      for (int i = 0; i < 2; ++i) af[i] = *(const bf16x8*)&sA[wr * 32 + i * 16 + ln][ks + qd * 8];
#pragma unroll
      for (int j = 0; j < 4; ++j) bfv[j] = *(const bf16x8*)&sB[wc * 64 + j * 16 + ln][ks + qd * 8];
#pragma unroll
      for (int i = 0; i < 2; ++i)
#pragma unroll
        for (int j = 0; j < 4; ++j) acc[i][j] = MFMA16(af[i], bfv[j], acc[i][j]);
    }
  }

#pragma unroll
  for (int i = 0; i < 2; ++i)
#pragma unroll
    for (int j = 0; j < 4; ++j)
#pragma unroll
      for (int r = 0; r < 4; ++r) {
        const int row = m0 + wr * 32 + i * 16 + qd * 4 + r;
        const int col = n0 + wc * 64 + j * 16 + ln;
        float v = acc[i][j][r] * scale;
        if (bias) v += bias[col];
        if (OUT_BF16)
          ((__bf16*)Cout)[(size_t)row * N + col] = (__bf16)v;
        else
          ((float*)Cout)[(size_t)row * N + col] = v;
      }
}

// fused Q/K/V projection: blockIdx.z selects {Xq@Wq*0.125, Xk@Wk, Xv@Wv}
__global__ __launch_bounds__(256) void gemm_qkv(const __bf16* __restrict__ Xq,
                                                const __bf16* __restrict__ Xk,
                                                const __bf16* __restrict__ Xv,
                                                const __bf16* __restrict__ WqT,
                                                const __bf16* __restrict__ WkT,
                                                const __bf16* __restrict__ WvT,
                                                __bf16* __restrict__ Qb,
                                                __bf16* __restrict__ Kb,
                                                __bf16* __restrict__ Vb) {
  const __bf16 *A, *B;
  __bf16* O;
  float sc;
  switch (blockIdx.z) {
    case 0: A = Xq; B = WqT; O = Qb; sc = 0.125f; break;
    case 1: A = Xk; B = WkT; O = Kb; sc = 1.0f; break;
    default: A = Xv; B = WvT; O = Vb; sc = 1.0f; break;
  }
  gemm64_body<true>(A, B, (void*)O, nullptr, sc);
}

// output projection: H_cat @ W_hidden + b, fp32 out
__global__ __launch_bounds__(256) void gemm_h(const __bf16* __restrict__ Hc,
                                              const __bf16* __restrict__ WhT,
                                              float* __restrict__ Hout,
                                              const float* __restrict__ bh) {
  gemm64_body<false>(Hc, WhT, (void*)Hout, bh, 1.0f);
}

// ---------------- fused sigmoid attention per (q-tile, head, batch) ----------------
// 64 q-rows per block, grid 32x16x2 = 1024 blocks -> 4 blocks/CU (LDS 34.5 KB).
// Q held in registers. S-tile 64x128 per iter; A written fp32 DIRECT from regs.
__global__ __launch_bounds__(256) void attn(const __bf16* __restrict__ Q,
                                            const __bf16* __restrict__ Kb,
                                            const __bf16* __restrict__ Vb,
                                            float* __restrict__ Aout,
                                            __bf16* __restrict__ Hc) {
  const int qt = blockIdx.x, h = blockIdx.y, b = blockIdx.z;
  const int tid = threadIdx.x, wave = tid >> 6, lane = tid & 63;
  const int qd = lane >> 4, ln = lane & 15;
  const int q0 = qt * 64;
  const int wr = wave >> 1, wc = wave & 1;

  // stride 132: V^T write conflicts 4-way (vs 8-way at 136); reads conflict-free via b64 pairs
  __shared__ __align__(16) __bf16 sVt[64][132];
  // aliased: K tile [128][72] (9216 el), then P tile [64][136] (8704 el)
  __shared__ __align__(16) __bf16 sKA[128 * 72];

  // Q fragments in registers for the whole kernel (16 VGPRs)
  const __bf16* Qg = Q + (size_t)(b * 2048 + q0) * 1024 + h * 64;
  bf16x8 qf[2][2];
#pragma unroll
  for (int i = 0; i < 2; ++i)
#pragma unroll
    for (int s = 0; s < 2; ++s)
      qf[i][s] = *(const bf16x8*)(Qg + (size_t)(wr * 32 + i * 16 + ln) * 1024 + s * 32 + qd * 8);

  f32x4 hacc[4] = {};
  float* Ag = Aout + ((size_t)((b * 16 + h) * 2048 + q0)) * 2048;

  for (int kt = 0; kt < 16; ++kt) {
    const int k0 = kt * 128;
    __syncthreads();  // prev iter's sKA(P)/sVt consumers done

    const __bf16* Kg = Kb + (size_t)(b * 2048 + k0) * 1024 + h * 64;
    const __bf16* Vg = Vb + (size_t)(b * 2048 + k0) * 1024 + h * 64;
#pragma unroll
    for (int p = 0; p < 4; ++p) {
      const int idx = p * 256 + tid, row = idx >> 3, ch = (idx & 7) * 8;
      *(bf16x8*)&sKA[row * 72 + ch] = *(const bf16x8*)(Kg + (size_t)row * 1024 + ch);
      bf16x8 v = *(const bf16x8*)(Vg + (size_t)row * 1024 + ch);
#pragma unroll
      for (int e = 0; e < 8; ++e) sVt[ch + e][row] = v[e];
    }
    __syncthreads();

    // S = Q·K^T : wave (wr,wc) owns 32 q-rows x 64 k-cols
    f32x4 sacc[2][4] = {};
#pragma unroll
    for (int ks = 0; ks < 64; ks += 32) {
      bf16x8 bfv[4];
#pragma unroll
      for (int j = 0; j < 4; ++j)
        bfv[j] = *(const bf16x8*)&sKA[(wc * 64 + j * 16 + ln) * 72 + ks + qd * 8];
#pragma unroll
      for (int i = 0; i < 2; ++i)
#pragma unroll
        for (int j = 0; j < 4; ++j) sacc[i][j] = MFMA16(qf[i][ks / 32], bfv[j], sacc[i][j]);
    }
    __syncthreads();  // all waves done reading K before aliasing as P

    // sigmoid -> direct fp32 A store (full precision) + bf16 P tile into sKA
#pragma unroll
    for (int i = 0; i < 2; ++i)
#pragma unroll
      for (int j = 0; j < 4; ++j)
#pragma unroll
        for (int r = 0; r < 4; ++r) {
          const float s = sacc[i][j][r];
          const float a = 1.0f / (1.0f + __expf(-s));
          const int rr = wr * 32 + i * 16 + qd * 4 + r;
          const int cc = wc * 64 + j * 16 + ln;
          Ag[(size_t)rr * 2048 + k0 + cc] = a;
          sKA[rr * 136 + cc] = (__bf16)a;
        }
    __syncthreads();

    // H += P·V : each wave owns 16 q-rows, all 64 d-cols
#pragma unroll
    for (int ks = 0; ks < 128; ks += 32) {
      bf16x8 pa = *(const bf16x8*)&sKA[(wave * 16 + ln) * 136 + ks + qd * 8];
#pragma unroll
      for (int j = 0; j < 4; ++j) {
        const __bf16* vp = &sVt[j * 16 + ln][ks + qd * 8];
        bf16x4 lo = *(const bf16x4*)vp;
        bf16x4 hi = *(const bf16x4*)(vp + 4);
        bf16x8 bv;
#pragma unroll
        for (int e = 0; e < 4; ++e) { bv[e] = lo[e]; bv[e + 4] = hi[e]; }
        hacc[j] = MFMA16(pa, bv, hacc[j]);
      }
    }
  }

  __bf16* Hg = Hc + (size_t)(b * 2048 + q0) * 1024 + h * 64;
#pragma unroll
  for (int j = 0; j < 4; ++j)
#pragma unroll
    for (int r = 0; r < 4; ++r)
      Hg[(size_t)(wave * 16 + qd * 4 + r) * 1024 + j * 16 + ln] = (__bf16)hacc[j][r];
}

extern "C" void kernel_launch(void* const* d_in, const int* in_sizes, int n_in,
                              void* d_out, int out_size, void* d_ws, size_t ws_size,
                              hipStream_t stream) {
  const float* Xq = (const float*)d_in[0];
  const float* Xk = (const float*)d_in[1];
  const float* Xv = (const float*)d_in[2];
  const float* Wq = (const float*)d_in[3];
  const float* Wk = (const float*)d_in[4];
  const float* Wv = (const float*)d_in[5];
  const float* Wh = (const float*)d_in[6];
  const float* bh = (const float*)d_in[7];

  float* Hout = (float*)d_out;               // 4096 x 1024 fp32
  float* Aout = Hout + (size_t)4096 * 1024;  // 2 x 16 x 2048 x 2048 fp32

  // workspace layout (bf16)
  __bf16* p = (__bf16*)d_ws;
  __bf16* Xq_bf = p; p += (size_t)4096 * 1024;
  __bf16* Xk_bf = p; p += (size_t)4096 * 1024;
  __bf16* Xv_bf = p; p += (size_t)4096 * 1024;
  __bf16* WqT = p; p += (size_t)1024 * 1024;
  __bf16* WkT = p; p += (size_t)1024 * 1024;
  __bf16* WvT = p; p += (size_t)1024 * 1024;
  __bf16* WhT = p; p += (size_t)1024 * 1024;
  __bf16* Qb = p; p += (size_t)4096 * 1024;
  __bf16* Kb = p; p += (size_t)4096 * 1024;
  __bf16* Vb = p; p += (size_t)4096 * 1024;
  __bf16* Hc = p; p += (size_t)4096 * 1024;

  cvt3<<<dim3(4096, 3), 256, 0, stream>>>(Xq, Xk, Xv, Xq_bf, Xk_bf, Xv_bf);
  twt<<<dim3(32, 32, 4), 256, 0, stream>>>(Wq, Wk, Wv, Wh, WqT, WkT, WvT, WhT);

  // one launch for Q, K, V projections (z = 0,1,2); Q has 1/sqrt(dk)=0.125 fused
  gemm_qkv<<<dim3(8, 64, 3), 256, 0, stream>>>(Xq_bf, Xk_bf, Xv_bf, WqT, WkT, WvT, Qb, Kb, Vb);

  attn<<<dim3(32, 16, 2), 256, 0, stream>>>(Qb, Kb, Vb, Aout, Hc);

  gemm_h<<<dim3(8, 64), 256, 0, stream>>>(Hc, WhT, Hout, bh);
}

// Round 3
// 739.085 us; speedup vs baseline: 1.3209x; 1.1720x over previous
//
#include <hip/hip_runtime.h>
#include <hip/hip_bf16.h>
#include <cstddef>

typedef __bf16 bf16x8 __attribute__((ext_vector_type(8)));
typedef __bf16 bf16x4 __attribute__((ext_vector_type(4)));
typedef float f32x4 __attribute__((ext_vector_type(4)));

#define MFMA16(a, b, c) __builtin_amdgcn_mfma_f32_16x16x32_bf16((a), (b), (c), 0, 0, 0)

// LDS-only barrier: producers/consumers are all ds ops; global loads stay in flight.
#define LBAR()                                           \
  do {                                                   \
    asm volatile("s_waitcnt lgkmcnt(0)" ::: "memory");   \
    __builtin_amdgcn_s_barrier();                        \
    __builtin_amdgcn_sched_barrier(0);                   \
  } while (0)

// ---------------- fp32 -> bf16 convert (X_q, X_k, X_v) ----------------
__global__ __launch_bounds__(256) void cvt3(const float* __restrict__ a,
                                            const float* __restrict__ b,
                                            const float* __restrict__ c,
                                            __bf16* __restrict__ oa,
                                            __bf16* __restrict__ ob,
                                            __bf16* __restrict__ oc) {
  const float* src = blockIdx.y == 0 ? a : (blockIdx.y == 1 ? b : c);
  __bf16* dst = blockIdx.y == 0 ? oa : (blockIdx.y == 1 ? ob : oc);
  const size_t i = ((size_t)blockIdx.x * 256 + threadIdx.x) * 4;
  float4 v = *(const float4*)(src + i);
  bf16x4 o = {(__bf16)v.x, (__bf16)v.y, (__bf16)v.z, (__bf16)v.w};
  *(bf16x4*)(dst + i) = o;
}

// ---------------- W [in][out] fp32 -> W^T [out][in] bf16 ----------------
__global__ __launch_bounds__(256) void twt(const float* __restrict__ w0, const float* __restrict__ w1,
                                           const float* __restrict__ w2, const float* __restrict__ w3,
                                           __bf16* __restrict__ o0, __bf16* __restrict__ o1,
                                           __bf16* __restrict__ o2, __bf16* __restrict__ o3) {
  const float* W;
  __bf16* O;
  switch (blockIdx.z) {
    case 0: W = w0; O = o0; break;
    case 1: W = w1; O = o1; break;
    case 2: W = w2; O = o2; break;
    default: W = w3; O = o3; break;
  }
  __shared__ float t[32][33];
  const int tx = threadIdx.x & 31, ty = threadIdx.x >> 5;
  const int bx = blockIdx.x * 32, by = blockIdx.y * 32;
#pragma unroll
  for (int i = 0; i < 4; ++i)
    t[ty + 8 * i][tx] = W[(size_t)(by + ty + 8 * i) * 1024 + bx + tx];
  __syncthreads();
#pragma unroll
  for (int i = 0; i < 4; ++i)
    O[(size_t)(bx + ty + 8 * i) * 1024 + by + tx] = (__bf16)t[tx][ty + 8 * i];
}

// ---------------- C = A @ B^T  (64x128 tile, BK=64, 4 waves of 32x64) ----------
// A rows at m0.., B rows at n0.., K = 1024. Output C[row][col] with row stride ostride.
template <bool OUT_BF16>
__device__ __forceinline__ void gemm64_body(const __bf16* __restrict__ A,
                                            const __bf16* __restrict__ B,
                                            void* __restrict__ Cout,
                                            const float* __restrict__ bias,
                                            float scale, int m0, int n0, int ostride) {
  constexpr int K = 1024;
  const int tid = threadIdx.x, wave = tid >> 6, lane = tid & 63;
  const int qd = lane >> 4, ln = lane & 15;
  const int wr = wave & 1, wc = wave >> 1;

  __shared__ __align__(16) __bf16 sA[64][72];
  __shared__ __align__(16) __bf16 sB[128][72];

  f32x4 acc[2][4] = {};

  const int sr = tid >> 2, sc = (tid & 3) * 8;  // 4 lanes cover 64B contiguous

  for (int k0 = 0; k0 < K; k0 += 64) {
    __syncthreads();
    *(bf16x8*)&sA[sr][sc]      = *(const bf16x8*)(A + (size_t)(m0 + sr) * K + k0 + sc);
    *(bf16x8*)&sA[sr][sc + 32] = *(const bf16x8*)(A + (size_t)(m0 + sr) * K + k0 + sc + 32);
#pragma unroll
    for (int h = 0; h < 128; h += 64)
#pragma unroll
      for (int c = 0; c < 64; c += 32)
        *(bf16x8*)&sB[sr + h][sc + c] =
            *(const bf16x8*)(B + (size_t)(n0 + sr + h) * K + k0 + sc + c);
    __syncthreads();

#pragma unroll
    for (int ks = 0; ks < 64; ks += 32) {
      bf16x8 af[2], bfv[4];
#pragma unroll
      for (int i = 0; i < 2; ++i) af[i] = *(const bf16x8*)&sA[wr * 32 + i * 16 + ln][ks + qd * 8];
#pragma unroll
      for (int j = 0; j < 4; ++j) bfv[j] = *(const bf16x8*)&sB[wc * 64 + j * 16 + ln][ks + qd * 8];
#pragma unroll
      for (int i = 0; i < 2; ++i)
#pragma unroll
        for (int j = 0; j < 4; ++j) acc[i][j] = MFMA16(af[i], bfv[j], acc[i][j]);
    }
  }

#pragma unroll
  for (int i = 0; i < 2; ++i)
#pragma unroll
    for (int j = 0; j < 4; ++j)
#pragma unroll
      for (int r = 0; r < 4; ++r) {
        const int row = m0 + wr * 32 + i * 16 + qd * 4 + r;
        const int col = n0 + wc * 64 + j * 16 + ln;
        float v = acc[i][j][r] * scale;
        if (bias) v += bias[col];
        if (OUT_BF16)
          ((__bf16*)Cout)[(size_t)row * ostride + col] = (__bf16)v;
        else
          ((float*)Cout)[(size_t)row * ostride + col] = v;
      }
}

// fused projections: z=0 -> Q = Xq@Wq*0.125 [4096x1024]; z=1 -> K = Xk@Wk [4096x1024];
// z=2 -> Vt = WvT @ Xv^T, output [1024][4096] (V transposed globally, per-head rows).
__global__ __launch_bounds__(256) void gemm_qkv(const __bf16* __restrict__ Xq,
                                                const __bf16* __restrict__ Xk,
                                                const __bf16* __restrict__ Xv,
                                                const __bf16* __restrict__ WqT,
                                                const __bf16* __restrict__ WkT,
                                                const __bf16* __restrict__ WvT,
                                                __bf16* __restrict__ Qb,
                                                __bf16* __restrict__ Kb,
                                                __bf16* __restrict__ Vt) {
  const int z = blockIdx.z;
  if (z < 2) {
    gemm64_body<true>(z ? Xk : Xq, z ? WkT : WqT, (void*)(z ? Kb : Qb), nullptr,
                      z ? 1.0f : 0.125f, blockIdx.y * 64, blockIdx.x * 128, 1024);
  } else {
    // remap (8,64) -> (32,16): 1024 output rows (d), 4096 output cols (b*2048+s)
    const int xp = blockIdx.x + (blockIdx.y & 3) * 8;
    const int yp = blockIdx.y >> 2;
    gemm64_body<true>(WvT, Xv, (void*)Vt, nullptr, 1.0f, yp * 64, xp * 128, 4096);
  }
}

// output projection: H_cat @ W_hidden + b, fp32 out
__global__ __launch_bounds__(256) void gemm_h(const __bf16* __restrict__ Hc,
                                              const __bf16* __restrict__ WhT,
                                              float* __restrict__ Hout,
                                              const float* __restrict__ bh) {
  gemm64_body<false>(Hc, WhT, (void*)Hout, bh, 1.0f, blockIdx.y * 64, blockIdx.x * 128, 1024);
}

// ---------------- fused sigmoid attention per (q-tile, head, batch) ----------------
// 64 q-rows per block, grid 32x16x2 = 1024 blocks. LDS 35.8 KB.
// Q in registers; K/Vt tile kt+1 prefetched to registers (T14); swapped QK^T (S^T)
// so A-stores are contiguous float4 nontemporal; V^T read directly from global Vt.
__global__ __launch_bounds__(256, 3) void attn(const __bf16* __restrict__ Q,
                                               const __bf16* __restrict__ Kb,
                                               const __bf16* __restrict__ Vt,
                                               float* __restrict__ Aout,
                                               __bf16* __restrict__ Hc) {
  const int qt = blockIdx.x, h = blockIdx.y, b = blockIdx.z;
  const int tid = threadIdx.x, wave = tid >> 6, lane = tid & 63;
  const int qd = lane >> 4, ln = lane & 15;
  const int q0 = qt * 64;
  const int wr = wave >> 1, wc = wave & 1;

  // sK: K tile [128 kv][72] (18.4 KB); aliased as sP [64 q][136 kv] (17.4 KB)
  __shared__ __align__(16) __bf16 sK[128 * 72];
  // sVt: V^T tile [64 d][136] (17.4 KB), staged with vector writes (no transpose)
  __shared__ __align__(16) __bf16 sVt[64 * 136];
  __bf16* sP = sK;

  // Q fragments in registers (16 VGPRs)
  const __bf16* Qg = Q + (size_t)(b * 2048 + q0) * 1024 + h * 64;
  bf16x8 qf[2][2];
#pragma unroll
  for (int i = 0; i < 2; ++i)
#pragma unroll
    for (int s = 0; s < 2; ++s)
      qf[i][s] = *(const bf16x8*)(Qg + (size_t)(wr * 32 + i * 16 + ln) * 1024 + s * 32 + qd * 8);

  // prefetch addressing
  const int krow = tid >> 3, kcol = (tid & 7) * 8;   // K: rows p*32+krow, col kcol
  const int vrow = tid >> 4, vcol = (tid & 15) * 8;  // Vt: rows p*16+vrow, col vcol
  const __bf16* Kg0 = Kb + (size_t)(b * 2048) * 1024 + h * 64;
  const __bf16* Vg0 = Vt + (size_t)(h * 64) * 4096 + b * 2048;

  bf16x8 kpre[4], vpre[4];
#pragma unroll
  for (int p = 0; p < 4; ++p) {
    kpre[p] = *(const bf16x8*)(Kg0 + (size_t)(p * 32 + krow) * 1024 + kcol);
    vpre[p] = *(const bf16x8*)(Vg0 + (size_t)(p * 16 + vrow) * 4096 + vcol);
  }

  f32x4 hacc[4] = {};
  float* Ag = Aout + ((size_t)((b * 16 + h) * 2048 + q0)) * 2048;

  for (int kt = 0; kt < 16; ++kt) {
    const int k0 = kt * 128;
    LBAR();  // prev iter's LDS readers (QK/PV) done before overwrite

    // regs -> LDS staging (compiler inserts vmcnt wait on kpre/vpre here)
#pragma unroll
    for (int p = 0; p < 4; ++p) {
      *(bf16x8*)&sK[(p * 32 + krow) * 72 + kcol] = kpre[p];
      *(bf16x8*)&sVt[(p * 16 + vrow) * 136 + vcol] = vpre[p];
    }
    LBAR();  // staging visible

    // issue next tile's global loads; they fly under QK/sigmoid/PV
    if (kt < 15) {
      const int kn = k0 + 128;
#pragma unroll
      for (int p = 0; p < 4; ++p) {
        kpre[p] = *(const bf16x8*)(Kg0 + (size_t)(kn + p * 32 + krow) * 1024 + kcol);
        vpre[p] = *(const bf16x8*)(Vg0 + (size_t)(p * 16 + vrow) * 4096 + kn + vcol);
      }
    }

    // S^T = K·Q^T (swapped operands): lane holds S[q = wr*32+i*16+ln][kv = wc*64+j*16+qd*4+r]
    f32x4 sacc[2][4] = {};
#pragma unroll
    for (int s = 0; s < 2; ++s) {
      bf16x8 kf[4];
#pragma unroll
      for (int j = 0; j < 4; ++j)
        kf[j] = *(const bf16x8*)&sK[(wc * 64 + j * 16 + ln) * 72 + s * 32 + qd * 8];
#pragma unroll
      for (int i = 0; i < 2; ++i)
#pragma unroll
        for (int j = 0; j < 4; ++j) sacc[i][j] = MFMA16(kf[j], qf[i][s], sacc[i][j]);
    }
    LBAR();  // all waves done reading sK before sP aliases it

    // sigmoid -> contiguous float4 nontemporal A-store + bf16x4 P-write
#pragma unroll
    for (int i = 0; i < 2; ++i)
#pragma unroll
      for (int j = 0; j < 4; ++j) {
        float a[4];
#pragma unroll
        for (int r = 0; r < 4; ++r) {
          const float e = __expf(-sacc[i][j][r]);
          a[r] = __builtin_amdgcn_rcpf(1.0f + e);
        }
        const int qrow = wr * 32 + i * 16 + ln;
        const int kcol2 = wc * 64 + j * 16 + qd * 4;
        f32x4 st = {a[0], a[1], a[2], a[3]};
        __builtin_nontemporal_store(st, (f32x4*)(Ag + (size_t)qrow * 2048 + k0 + kcol2));
        bf16x4 pb = {(__bf16)a[0], (__bf16)a[1], (__bf16)a[2], (__bf16)a[3]};
        *(bf16x4*)&sP[qrow * 136 + kcol2] = pb;
      }
    LBAR();  // P visible

    // H += P·V : wave owns 16 q-rows, all 64 d-cols
#pragma unroll
    for (int ks = 0; ks < 128; ks += 32) {
      bf16x8 pa = *(const bf16x8*)&sP[(wave * 16 + ln) * 136 + ks + qd * 8];
#pragma unroll
      for (int j = 0; j < 4; ++j) {
        bf16x8 bv = *(const bf16x8*)&sVt[(j * 16 + ln) * 136 + ks + qd * 8];
        hacc[j] = MFMA16(pa, bv, hacc[j]);
      }
    }
  }

  __bf16* Hg = Hc + (size_t)(b * 2048 + q0) * 1024 + h * 64;
#pragma unroll
  for (int j = 0; j < 4; ++j)
#pragma unroll
    for (int r = 0; r < 4; ++r)
      Hg[(size_t)(wave * 16 + qd * 4 + r) * 1024 + j * 16 + ln] = (__bf16)hacc[j][r];
}

extern "C" void kernel_launch(void* const* d_in, const int* in_sizes, int n_in,
                              void* d_out, int out_size, void* d_ws, size_t ws_size,
                              hipStream_t stream) {
  const float* Xq = (const float*)d_in[0];
  const float* Xk = (const float*)d_in[1];
  const float* Xv = (const float*)d_in[2];
  const float* Wq = (const float*)d_in[3];
  const float* Wk = (const float*)d_in[4];
  const float* Wv = (const float*)d_in[5];
  const float* Wh = (const float*)d_in[6];
  const float* bh = (const float*)d_in[7];

  float* Hout = (float*)d_out;               // 4096 x 1024 fp32
  float* Aout = Hout + (size_t)4096 * 1024;  // 2 x 16 x 2048 x 2048 fp32

  // workspace layout (bf16)
  __bf16* p = (__bf16*)d_ws;
  __bf16* Xq_bf = p; p += (size_t)4096 * 1024;
  __bf16* Xk_bf = p; p += (size_t)4096 * 1024;
  __bf16* Xv_bf = p; p += (size_t)4096 * 1024;
  __bf16* WqT = p; p += (size_t)1024 * 1024;
  __bf16* WkT = p; p += (size_t)1024 * 1024;
  __bf16* WvT = p; p += (size_t)1024 * 1024;
  __bf16* WhT = p; p += (size_t)1024 * 1024;
  __bf16* Qb = p; p += (size_t)4096 * 1024;
  __bf16* Kb = p; p += (size_t)4096 * 1024;
  __bf16* Vt = p; p += (size_t)1024 * 4096;  // V^T: [1024 d][4096 = b*2048+s]
  __bf16* Hc = p; p += (size_t)4096 * 1024;

  cvt3<<<dim3(4096, 3), 256, 0, stream>>>(Xq, Xk, Xv, Xq_bf, Xk_bf, Xv_bf);
  twt<<<dim3(32, 32, 4), 256, 0, stream>>>(Wq, Wk, Wv, Wh, WqT, WkT, WvT, WhT);

  // Q (scaled), K, and V^T projections in one launch
  gemm_qkv<<<dim3(8, 64, 3), 256, 0, stream>>>(Xq_bf, Xk_bf, Xv_bf, WqT, WkT, WvT, Qb, Kb, Vt);

  attn<<<dim3(32, 16, 2), 256, 0, stream>>>(Qb, Kb, Vt, Aout, Hc);

  gemm_h<<<dim3(8, 64), 256, 0, stream>>>(Hc, WhT, Hout, bh);
}